// Round 6
// baseline (399.654 us; speedup 1.0000x reference)
//
#include <hip/hip_runtime.h>

typedef _Float16 f16x8 __attribute__((ext_vector_type(8)));
typedef _Float16 f16x4 __attribute__((ext_vector_type(4)));
typedef float    f32x4 __attribute__((ext_vector_type(4)));
typedef int      i32x4 __attribute__((ext_vector_type(4)));

#define S_LEN 2048
#define D_KH  64
#define NBH   32                       // B*H
#define QTILE 16
#define THREADS 512                    // 8 waves
#define NBLOCKS 512                    // persistent: exactly 2 blocks/CU
#define NT 8                           // q-tiles per block (512*8 = 4096 tiles)
#define QK_ELEMS (NBH * S_LEN * D_KH)

__device__ __forceinline__ f16x8 cvt8(const float4 a, const float4 b) {
  f16x8 r;
  r[0] = (_Float16)a.x; r[1] = (_Float16)a.y;
  r[2] = (_Float16)a.z; r[3] = (_Float16)a.w;
  r[4] = (_Float16)b.x; r[5] = (_Float16)b.y;
  r[6] = (_Float16)b.z; r[7] = (_Float16)b.w;
  return r;
}

// Prep: K -> f16, q -> f16 pre-scaled by 1/sqrt(64).
__global__ __launch_bounds__(256) void cvt_qk_kernel(
    const float* __restrict__ q, const float* __restrict__ kmat,
    _Float16* __restrict__ qh, _Float16* __restrict__ kh) {
  const long long idx = ((long long)blockIdx.x * 256 + threadIdx.x) * 8;
  float4 q0 = *(const float4*)(q + idx);
  float4 q1 = *(const float4*)(q + idx + 4);
  const float s = 0.125f;
  q0.x *= s; q0.y *= s; q0.z *= s; q0.w *= s;
  q1.x *= s; q1.y *= s; q1.z *= s; q1.w *= s;
  *(f16x8*)(qh + idx) = cvt8(q0, q1);
  const float4 k0 = *(const float4*)(kmat + idx);
  const float4 k1 = *(const float4*)(kmat + idx + 4);
  *(f16x8*)(kh + idx) = cvt8(k0, k1);
}

// R4-style 3-pass softmax over an LDS f16 score row, mask as 32-bit field
// (bit 4i+j = mask for column (i<<8)+(l<<2)+j). Re-reads LDS per pass; no
// sv[] array -> low VGPR.
__device__ __forceinline__ void softmax_row_packed(
    const _Float16* __restrict__ srow, const unsigned pm, const int physx,
    const int l, float* __restrict__ op) {
  float mx = -3.0e38f;
  #pragma unroll
  for (int i = 0; i < 8; ++i) {
    const int off = (((i << 8) + (l << 2))) ^ physx;
    const f16x4 h = *(const f16x4*)&srow[off];
    const unsigned b = pm >> (4 * i);
    mx = fmaxf(mx, (b & 1u) ? -1.0e9f : (float)h[0]);
    mx = fmaxf(mx, (b & 2u) ? -1.0e9f : (float)h[1]);
    mx = fmaxf(mx, (b & 4u) ? -1.0e9f : (float)h[2]);
    mx = fmaxf(mx, (b & 8u) ? -1.0e9f : (float)h[3]);
  }
  #pragma unroll
  for (int off = 32; off > 0; off >>= 1)
    mx = fmaxf(mx, __shfl_xor(mx, off, 64));
  float sum = 0.f;
  #pragma unroll
  for (int i = 0; i < 8; ++i) {
    const int off = (((i << 8) + (l << 2))) ^ physx;
    const f16x4 h = *(const f16x4*)&srow[off];
    const unsigned b = pm >> (4 * i);
    sum += (b & 1u) ? 0.f : __expf((float)h[0] - mx);
    sum += (b & 2u) ? 0.f : __expf((float)h[1] - mx);
    sum += (b & 4u) ? 0.f : __expf((float)h[2] - mx);
    sum += (b & 8u) ? 0.f : __expf((float)h[3] - mx);
  }
  #pragma unroll
  for (int off = 32; off > 0; off >>= 1)
    sum += __shfl_xor(sum, off, 64);
  const float inv = 1.0f / sum;
  #pragma unroll
  for (int i = 0; i < 8; ++i) {
    const int col = (i << 8) + (l << 2);
    const f16x4 h = *(const f16x4*)&srow[col ^ physx];
    const unsigned b = pm >> (4 * i);
    f32x4 o = { (b & 1u) ? 0.f : __expf((float)h[0] - mx) * inv,
                (b & 2u) ? 0.f : __expf((float)h[1] - mx) * inv,
                (b & 4u) ? 0.f : __expf((float)h[2] - mx) * inv,
                (b & 8u) ? 0.f : __expf((float)h[3] - mx) * inv };
    __builtin_nontemporal_store(o, (f32x4*)(op + col));
  }
}

template <bool F16>
__global__ __launch_bounds__(THREADS, 4) void sdpa_probs_kernel(
    const float* __restrict__ qf, const float* __restrict__ kf,
    const _Float16* __restrict__ qh, const _Float16* __restrict__ kh,
    const int* __restrict__ mask, float* __restrict__ out) {
  // XCD swizzle: blocks 0..63 of nb on XCD0, etc. -> 4 heads/XCD, whose f16
  // K+q panels (4 x 512 KiB) stay hot in that XCD's 4 MiB L2 all kernel.
  const int bid = (int)blockIdx.x;
  const int nb  = (bid & 7) * (NBLOCKS / 8) + (bid >> 3);
  const int bh  = nb >> 4;    // head 0..31
  const int jb  = nb & 15;    // block-within-head; q-tiles jb*NT + t

  __shared__ _Float16 sc[QTILE][S_LEN];  // 64 KiB score strip

  const int tid   = (int)threadIdx.x;
  const int w     = tid >> 6;   // wave 0..7
  const int l     = tid & 63;
  const int lo    = l & 15;
  const int g     = l >> 4;
  const int dbase = g << 3;

  const size_t qk_bh = (size_t)bh * S_LEN * D_KH;
  const size_t obh   = (size_t)bh * S_LEN * S_LEN;

  const int rowA = w << 1, rowB = rowA | 1;  // wave w owns rows 2w, 2w+1
  const int physx = (w >> 1) << 4;           // rowA>>2 == rowB>>2 == w>>1

  i32x4 rawA[8], rawB[8];                    // in-flight masks (reused per t)

#define ISSUE_MASKS(qt_) do {                                                  \
    const int* mpA_ = mask + obh + (size_t)((qt_) * QTILE + rowA) * S_LEN + (l << 2); \
    const int* mpB_ = mask + obh + (size_t)((qt_) * QTILE + rowB) * S_LEN + (l << 2); \
    _Pragma("unroll")                                                          \
    for (int i_ = 0; i_ < 8; ++i_) {                                           \
      rawA[i_] = __builtin_nontemporal_load((const i32x4*)(mpA_ + (i_ << 8))); \
      rawB[i_] = __builtin_nontemporal_load((const i32x4*)(mpB_ + (i_ << 8))); \
    }                                                                          \
  } while (0)

  ISSUE_MASKS(jb * NT);   // prologue: tile 0 masks in flight

  for (int t = 0; t < NT; ++t) {
    const int qt = jb * NT + t;

    // ---- A fragments: q rows of this tile (pre-scaled) ----
    f16x8 a0, a1;
    if constexpr (F16) {
      const _Float16* qp = qh + qk_bh + (size_t)(qt * QTILE + lo) * D_KH + dbase;
      a0 = *(const f16x8*)qp;
      a1 = *(const f16x8*)(qp + 32);
    } else {
      const float* qp = qf + qk_bh + (size_t)(qt * QTILE + lo) * D_KH;
      float4 t0 = *(const float4*)(qp + dbase);
      float4 t1 = *(const float4*)(qp + dbase + 4);
      float4 t2 = *(const float4*)(qp + dbase + 32);
      float4 t3 = *(const float4*)(qp + dbase + 36);
      const float s = 0.125f;
      t0.x *= s; t0.y *= s; t0.z *= s; t0.w *= s;
      t1.x *= s; t1.y *= s; t1.z *= s; t1.w *= s;
      t2.x *= s; t2.y *= s; t2.z *= s; t2.w *= s;
      t3.x *= s; t3.y *= s; t3.z *= s; t3.w *= s;
      a0 = cvt8(t0, t1);
      a1 = cvt8(t2, t3);
    }

    // ---- Phase 1: scores via f16 MFMA; wave w owns keys [256w, 256w+256) ----
    #pragma unroll 2
    for (int kt = 0; kt < 16; ++kt) {
      const int kcol = (w << 8) + (kt << 4) + lo;
      f16x8 b0, b1;
      if constexpr (F16) {
        const _Float16* kp = kh + qk_bh + (size_t)kcol * D_KH + dbase;
        b0 = *(const f16x8*)kp;
        b1 = *(const f16x8*)(kp + 32);
      } else {
        const float* kp = kf + qk_bh + (size_t)kcol * D_KH + dbase;
        b0 = cvt8(*(const float4*)(kp), *(const float4*)(kp + 4));
        b1 = cvt8(*(const float4*)(kp + 32), *(const float4*)(kp + 36));
      }
      f32x4 acc = {0.f, 0.f, 0.f, 0.f};
      acc = __builtin_amdgcn_mfma_f32_16x16x32_f16(a0, b0, acc, 0, 0, 0);
      acc = __builtin_amdgcn_mfma_f32_16x16x32_f16(a1, b1, acc, 0, 0, 0);
      // D layout: row = 4g+r, col = lo. XOR-swizzle col bit4 by g -> 32 banks.
      const int phys = kcol ^ (g << 4);
      #pragma unroll
      for (int r = 0; r < 4; ++r)
        sc[(g << 2) + r][phys] = (_Float16)acc[r];
    }

    // ---- Compress this tile's masks (arrived during phase 1) to 2x u32 ----
    unsigned pA = 0, pB = 0;
    #pragma unroll
    for (int i = 0; i < 8; ++i) {
      pA |= ((rawA[i].x != 0 ? 1u : 0u) << (4 * i))
          | ((rawA[i].y != 0 ? 1u : 0u) << (4 * i + 1))
          | ((rawA[i].z != 0 ? 1u : 0u) << (4 * i + 2))
          | ((rawA[i].w != 0 ? 1u : 0u) << (4 * i + 3));
      pB |= ((rawB[i].x != 0 ? 1u : 0u) << (4 * i))
          | ((rawB[i].y != 0 ? 1u : 0u) << (4 * i + 1))
          | ((rawB[i].z != 0 ? 1u : 0u) << (4 * i + 2))
          | ((rawB[i].w != 0 ? 1u : 0u) << (4 * i + 3));
    }

    // ---- Issue next tile's masks: in flight across the barrier, overlapping
    //      this tile's phase-2 store stream (read+write HBM overlap). ----
    if (t + 1 < NT) ISSUE_MASKS(qt + 1);

    __syncthreads();   // scores ready

    // ---- Phase 2: softmax + store (pure VALU/LDS + store stream) ----
    const size_t orowA = obh + (size_t)(qt * QTILE + rowA) * S_LEN;
    const size_t orowB = obh + (size_t)(qt * QTILE + rowB) * S_LEN;
    softmax_row_packed(&sc[rowA][0], pA, physx, l, out + orowA);
    softmax_row_packed(&sc[rowB][0], pB, physx, l, out + orowB);

    __syncthreads();   // all sc reads done -> next iter may overwrite
  }
#undef ISSUE_MASKS
}

extern "C" void kernel_launch(void* const* d_in, const int* in_sizes, int n_in,
                              void* d_out, int out_size, void* d_ws, size_t ws_size,
                              hipStream_t stream) {
  const float* q    = (const float*)d_in[0];
  const float* kmat = (const float*)d_in[1];
  // d_in[2] = v, unused (reference stops at softmax)
  const int*   mask = (const int*)d_in[3];
  float*       out  = (float*)d_out;

  const size_t need = (size_t)QK_ELEMS * 2 * sizeof(_Float16);
  if (ws_size >= need) {
    _Float16* qh = (_Float16*)d_ws;
    _Float16* kh = qh + QK_ELEMS;
    cvt_qk_kernel<<<dim3(QK_ELEMS / 8 / 256), dim3(256), 0, stream>>>(q, kmat, qh, kh);
    sdpa_probs_kernel<true><<<dim3(NBLOCKS), dim3(THREADS), 0, stream>>>(
        nullptr, nullptr, qh, kh, mask, out);
  } else {
    sdpa_probs_kernel<false><<<dim3(NBLOCKS), dim3(THREADS), 0, stream>>>(
        q, kmat, nullptr, nullptr, mask, out);
  }
}